// Round 13
// baseline (18.976 us; speedup 1.0000x reference)
//
#include <hip/hip_runtime.h>

// DichotomicSolver: per-row root-find of Dm(m)=mean(sigmoid(30(m-x)))-0.5.
// R13: in-drain staging (R12's overlap idea) + R8's exact math/trajectory.
// Per chunk AS LOADS ARRIVE: membership in fixed staging band [42,58),
// DPP-scan ranks, scatter to per-wave LDS, plus counts of x<42 and x<50 ->
// all hidden under the memory drain. Post-drain (tiny critical path):
//   c0 = 50 + (1024 - n50)/20.48   (same estimator as R8; error ~ +-0.8)
//   Newton INIT at c0, bracket [c0-1.1, c0+1.1]  (reference's stop-point
//   clusters near the count-median; starting there reproduces R8's absmax
//   0.75 in near-flat gap regions -- R12's fixed-bracket init caused 3.25)
//   D evaluated over 7 staged regs/lane with exact sigmoids + n42 as 1.0s.
// Exactness for m in bracket (c0 in [44.9,55.1] guard):
//   x < 42  => 30*(m-x) >= 30*0.6=18 => sigmoid == 1.0f bit-exact
//   x >= 58 => sigma <= e^-54, * 2048 ~ 1e-20 -> dropped
//   staged x outside [c0+-1.7] self-saturate (difference vs R8 ~5e-10 in D).
// Guards (wave-uniform): k <= 448, c0 in range, D(Lb)<0<D(Rb); else fallback
// (reload row: 16-step ballot bisection + 3 clamped Newton = R5's path).

constexpr int   S_DIM = 2048;
constexpr int   EPL   = S_DIM / 64;            // 32 elements per lane
constexpr float KL2E  = 43.280851308343876f;   // 30 * log2(e)
constexpr float SLO   = 42.0f, SHI = 58.0f;    // fixed staging band
constexpr int   CAP   = 448;                   // 7 regs/lane (mean 328, ~6 sigma)
constexpr float BRH   = 1.1f;                  // Newton bracket half-width
constexpr int   NNEWT = 4;

template<int CTRL, int RMASK>
__device__ __forceinline__ int dpp_add_i(int v) {
    return v + __builtin_amdgcn_update_dpp(0, v, CTRL, RMASK, 0xF, true);
}

// wave64 inclusive +scan (gfx9 row_shr/row_bcast sequence)
__device__ __forceinline__ int wave_iscan_incl(int v) {
    v = dpp_add_i<0x111, 0xF>(v);
    v = dpp_add_i<0x112, 0xF>(v);
    v = dpp_add_i<0x114, 0xF>(v);
    v = dpp_add_i<0x118, 0xF>(v);
    v = dpp_add_i<0x142, 0xA>(v);
    v = dpp_add_i<0x143, 0xC>(v);
    return v;
}

template<int CTRL>
__device__ __forceinline__ float dpp_add_f(float v) {
    int sh = __builtin_amdgcn_update_dpp(0, __float_as_int(v), CTRL, 0xF, 0xF, true);
    return v + __int_as_float(sh);
}

// full wave64 sum broadcast (pure VALU DPP + readlane)
__device__ __forceinline__ float wave_reduce_bcast(float v) {
    v = dpp_add_f<0x111>(v);
    v = dpp_add_f<0x112>(v);
    v = dpp_add_f<0x114>(v);
    v = dpp_add_f<0x118>(v);
    v = dpp_add_f<0x142>(v);
    v = dpp_add_f<0x143>(v);
    return __int_as_float(__builtin_amdgcn_readlane(__float_as_int(v), 63));
}

__device__ __forceinline__ float sig(float xv, float m) {
    float e = __builtin_amdgcn_exp2f((xv - m) * KL2E);
    return __builtin_amdgcn_rcpf(1.0f + e);
}

__global__ __launch_bounds__(256)
void dicho_kernel(const float* __restrict__ x, float* __restrict__ out, int bs) {
    __shared__ float band[4][CAP];       // per-wave private slice, no barriers

    const int wid  = threadIdx.x >> 6;   // 0..3
    const int lane = threadIdx.x & 63;
    const int row  = blockIdx.x * 4 + wid;
    if (row >= bs) return;               // barrier-free -> early return safe
    float* bandp = band[wid];

    const float4* xr = reinterpret_cast<const float4*>(x + (size_t)row * S_DIM);

    // ---- In-drain: per-chunk membership + scan + scatter + counts ----
    int cpk = 0;   // (count x<42) << 16 | (count x<50)
    int k   = 0;   // wave-uniform running staging cursor
    #pragma unroll
    for (int j = 0; j < EPL / 4; ++j) {
        const float4 v = xr[j * 64 + lane];
        const bool m0 = (v.x >= SLO) && (v.x < SHI);
        const bool m1 = (v.y >= SLO) && (v.y < SHI);
        const bool m2 = (v.z >= SLO) && (v.z < SHI);
        const bool m3 = (v.w >= SLO) && (v.w < SHI);
        cpk += ((v.x < SLO) ? 0x10000 : 0) + ((v.x < 50.0f) ? 1 : 0)
             + ((v.y < SLO) ? 0x10000 : 0) + ((v.y < 50.0f) ? 1 : 0)
             + ((v.z < SLO) ? 0x10000 : 0) + ((v.z < 50.0f) ? 1 : 0)
             + ((v.w < SLO) ? 0x10000 : 0) + ((v.w < 50.0f) ? 1 : 0);
        const int mb   = (int)m0 + (int)m1 + (int)m2 + (int)m3;
        const int incl = wave_iscan_incl(mb);
        int base = k + incl - mb;                 // exclusive rank
        if (m0) { if (base < CAP) bandp[base] = v.x; base++; }
        if (m1) { if (base < CAP) bandp[base] = v.y; base++; }
        if (m2) { if (base < CAP) bandp[base] = v.z; base++; }
        if (m3) { if (base < CAP) bandp[base] = v.w; base++; }
        k += __builtin_amdgcn_readlane(incl, 63); // wave-uniform
    }

    // ---- Post-drain: short critical path ----
    const int ptot = __builtin_amdgcn_readlane(wave_iscan_incl(cpk), 63);
    const int n42  = ptot >> 16;
    const int n50  = ptot & 0xffff;
    const float c0 = 50.0f + (float)(S_DIM / 2 - n50) * (100.0f / (float)S_DIM);

    float m = 0.0f;
    bool done = false;

    if (k <= CAP && c0 >= 44.9f && c0 <= 55.1f) {
        // Hoist staged band into 7 regs/lane; mask garbage via selects
        // (cndmask picks 0.0f regardless of NaN in the other operand).
        const bool  w0 = lane < k,       w1 = lane + 64  < k;
        const bool  w2 = lane + 128 < k, w3 = lane + 192 < k;
        const bool  w4 = lane + 256 < k, w5 = lane + 320 < k;
        const bool  w6 = lane + 384 < k;
        const float a0 = bandp[lane],       a1 = bandp[lane + 64];
        const float a2 = bandp[lane + 128], a3 = bandp[lane + 192];
        const float a4 = bandp[lane + 256], a5 = bandp[lane + 320];
        const float a6 = bandp[lane + 384];
        const float below = (float)n42;

        auto evalD = [&](float mm, float& D, float& Dp, bool needDp) {
            const float r0 = sig(a0, mm), r1 = sig(a1, mm), r2 = sig(a2, mm);
            const float r3 = sig(a3, mm), r4 = sig(a4, mm), r5 = sig(a5, mm);
            const float r6 = sig(a6, mm);
            float S = (w0 ? r0 : 0.0f) + (w1 ? r1 : 0.0f) + (w2 ? r2 : 0.0f)
                    + (w3 ? r3 : 0.0f) + (w4 ? r4 : 0.0f) + (w5 ? r5 : 0.0f)
                    + (w6 ? r6 : 0.0f);
            D = (wave_reduce_bcast(S) + below) * (1.0f / (float)S_DIM) - 0.5f;
            if (needDp) {
                float T = (w0 ? r0 * (1.0f - r0) : 0.0f)
                        + (w1 ? r1 * (1.0f - r1) : 0.0f)
                        + (w2 ? r2 * (1.0f - r2) : 0.0f)
                        + (w3 ? r3 * (1.0f - r3) : 0.0f)
                        + (w4 ? r4 * (1.0f - r4) : 0.0f)
                        + (w5 ? r5 * (1.0f - r5) : 0.0f)
                        + (w6 ? r6 * (1.0f - r6) : 0.0f);
                Dp = wave_reduce_bcast(T) * (30.0f / (float)S_DIM);
            }
        };

        // Root-in-bracket sign check (wave-uniform).
        float Lb = c0 - BRH, Rb = c0 + BRH;
        float DL, DR, dum;
        evalD(Lb, DL, dum, false);
        evalD(Rb, DR, dum, false);

        if (DL < 0.0f && DR > 0.0f) {
            // R8's exact Newton: init at c0, bracketed, 4 iterations.
            m = c0;
            #pragma unroll
            for (int t = 0; t < NNEWT; ++t) {
                float D, Dp;
                evalD(m, D, Dp, true);
                if (D > 0.0f) Rb = m; else Lb = m;
                float mn = m - D * __builtin_amdgcn_rcpf(Dp + 1e-20f);
                if (!(mn > Lb && mn < Rb)) mn = (Lb + Rb) * 0.5f;
                m = mn;
            }
            done = true;
        }
    }

    if (!done) {
        // ---- Fallback (rare/never for this input): reload row; 16-step
        //      ballot bisection + 3 clamped full-width Newton (R5's path). ----
        float xs[EPL];
        #pragma unroll
        for (int j = 0; j < EPL / 4; ++j) {
            float4 v = xr[j * 64 + lane];
            xs[4*j+0] = v.x; xs[4*j+1] = v.y; xs[4*j+2] = v.z; xs[4*j+3] = v.w;
        }
        float lo = 0.0f, hi = 100.0f;
        #pragma unroll 1
        for (int t = 0; t < 16; ++t) {
            const float c = (lo + hi) * 0.5f;
            int cnt = 0;
            #pragma unroll
            for (int j = 0; j < EPL; ++j)
                cnt += __popcll(__ballot(xs[j] < c));
            if (cnt >= S_DIM / 2) hi = c; else lo = c;
        }
        m = (lo + hi) * 0.5f;
        #pragma unroll 1
        for (int t = 0; t < 3; ++t) {
            float S = 0.0f, T = 0.0f;
            #pragma unroll
            for (int j = 0; j < EPL; ++j) {
                const float r = sig(xs[j], m);
                S += r;
                T += r * (1.0f - r);
            }
            S = wave_reduce_bcast(S);
            T = wave_reduce_bcast(T);
            const float D  = S * (1.0f / (float)S_DIM) - 0.5f;
            const float Dp = T * (30.0f / (float)S_DIM);
            float step = D * __builtin_amdgcn_rcpf(Dp + 1e-12f);
            step = fminf(0.5f, fmaxf(-0.5f, step));
            m -= step;
        }
    }

    if (lane == 0) out[row] = m;
}

extern "C" void kernel_launch(void* const* d_in, const int* in_sizes, int n_in,
                              void* d_out, int out_size, void* d_ws, size_t ws_size,
                              hipStream_t stream) {
    const float* x = (const float*)d_in[0];
    float* out = (float*)d_out;
    const int bs = out_size;               // 4096 rows, output [bs,1]
    const int blocks = (bs + 3) / 4;       // 4 waves (rows) per 256-thread block
    dicho_kernel<<<blocks, 256, 0, stream>>>(x, out, bs);
}

// Round 14
// 11.053 us; speedup vs baseline: 1.7168x; 1.7168x over previous
//
#include <hip/hip_runtime.h>

// DichotomicSolver: per-row root-find of Dm(m)=mean(sigmoid(30(m-x)))-0.5.
// R14 = R10 verbatim (proven best: 10.96 us, absmax 0.75). Restores best
// state after R13's in-drain staging regressed to 19 us (per-chunk scatter
// serialized the row loads). Structure: load-all-then-compute, 8 independent
// waves per 512-thread block, no __syncthreads, per-wave LDS band slices.
//   n50 count -> inverse-CDF c0; band |x-c0| <= 1.7 (cap 128 = 2 regs/lane;
//   below-band sigmoid == 1.0f bit-exact since 30*(1.7-1.1)=18; above-band
//   < 3e-5 counts); 4 bracketed-Newton iters in [c0-1.1, c0+1.1].
//   Fallback (never taken for this input): ballot bisection + clamped Newton.

constexpr int   S_DIM = 2048;
constexpr int   EPL   = S_DIM / 64;            // 32 elements per lane
constexpr float KL2E  = 43.280851308343876f;   // 30 * log2(e)
constexpr int   BANDC = 128;                   // band capacity (mean ~70, max ~102)
constexpr float BHW   = 1.7f;                  // band half-width
constexpr float MCL   = 1.1f;                  // Newton bracket half-width
constexpr int   NNEWT = 4;
constexpr int   WPB   = 8;                     // waves (rows) per block

template<int CTRL, int RMASK>
__device__ __forceinline__ int dpp_add_i(int v) {
    return v + __builtin_amdgcn_update_dpp(0, v, CTRL, RMASK, 0xF, true);
}

// wave64 inclusive +scan (gfx9 row_shr/row_bcast sequence)
__device__ __forceinline__ int wave_iscan_incl(int v) {
    v = dpp_add_i<0x111, 0xF>(v);
    v = dpp_add_i<0x112, 0xF>(v);
    v = dpp_add_i<0x114, 0xF>(v);
    v = dpp_add_i<0x118, 0xF>(v);
    v = dpp_add_i<0x142, 0xA>(v);
    v = dpp_add_i<0x143, 0xC>(v);
    return v;
}

template<int CTRL>
__device__ __forceinline__ float dpp_add_f(float v) {
    int sh = __builtin_amdgcn_update_dpp(0, __float_as_int(v), CTRL, 0xF, 0xF, true);
    return v + __int_as_float(sh);
}

// full wave64 sum broadcast (pure VALU DPP + readlane)
__device__ __forceinline__ float wave_reduce_bcast(float v) {
    v = dpp_add_f<0x111>(v);
    v = dpp_add_f<0x112>(v);
    v = dpp_add_f<0x114>(v);
    v = dpp_add_f<0x118>(v);
    v = dpp_add_f<0x142>(v);
    v = dpp_add_f<0x143>(v);
    return __int_as_float(__builtin_amdgcn_readlane(__float_as_int(v), 63));
}

__device__ __forceinline__ float sig(float xv, float m) {
    float e = __builtin_amdgcn_exp2f((xv - m) * KL2E);
    return __builtin_amdgcn_rcpf(1.0f + e);
}

__global__ __launch_bounds__(512)
void dicho_kernel(const float* __restrict__ x, float* __restrict__ out, int bs) {
    __shared__ float band[WPB][BANDC];   // per-wave private slice -> no barriers

    const int wid  = threadIdx.x >> 6;   // 0..7, one row per wave
    const int lane = threadIdx.x & 63;
    const int row  = blockIdx.x * WPB + wid;
    if (row >= bs) return;               // barrier-free -> early return safe

    // Coalesced load (8 x float4/lane); n50 counting interleaved.
    const float4* xr = reinterpret_cast<const float4*>(x + (size_t)row * S_DIM);
    float xs[EPL];
    int c50 = 0;
    #pragma unroll
    for (int j = 0; j < EPL / 4; ++j) {
        float4 v = xr[j * 64 + lane];
        xs[4*j+0] = v.x; xs[4*j+1] = v.y; xs[4*j+2] = v.z; xs[4*j+3] = v.w;
        c50 += (v.x < 50.0f) ? 1 : 0;
        c50 += (v.y < 50.0f) ? 1 : 0;
        c50 += (v.z < 50.0f) ? 1 : 0;
        c50 += (v.w < 50.0f) ? 1 : 0;
    }

    // ---- inverse-CDF estimate from n50 (one int DPP reduce) ----
    const int n50 = __builtin_amdgcn_readlane(wave_iscan_incl(c50), 63);
    float c0 = 50.0f + (float)(S_DIM / 2 - n50) * (100.0f / (float)S_DIM);
    c0 = fminf(100.0f, fmaxf(0.0f, c0));

    // ---- Band membership + exact ranks via ONE packed int DPP scan ----
    const float blo = c0 - BHW, bhi = c0 + BHW;
    int below_l = 0, nb_l = 0;
    #pragma unroll
    for (int j = 0; j < EPL; ++j) {
        below_l += (xs[j] < blo) ? 1 : 0;
        nb_l    += (xs[j] >= blo && xs[j] <= bhi) ? 1 : 0;
    }
    const int packed = (below_l << 16) | nb_l;
    const int pincl  = wave_iscan_incl(packed);
    const int ptot   = __builtin_amdgcn_readlane(pincl, 63);
    const int belowN = ptot >> 16;
    const int nbtot  = ptot & 0xffff;

    float m;
    const bool ok = (nbtot <= BANDC) && (belowN < S_DIM / 2)
                 && (belowN + nbtot > S_DIM / 2);        // wave-uniform
    if (ok) {
        // Scatter band to this wave's LDS slice at exact deterministic ranks.
        int k = (pincl - packed) & 0xffff;
        #pragma unroll
        for (int j = 0; j < EPL; ++j) {
            if (xs[j] >= blo && xs[j] <= bhi) band[wid][k++] = xs[j];
        }
        // Hoist into 2 regs/lane (in-wave DS ordering: no barrier needed).
        const bool  v0 = lane < nbtot, v1 = lane + 64 < nbtot;
        const float a0 = band[wid][lane];
        const float a1 = band[wid][lane + 64];
        const float below = (float)belowN;

        // Bracketed Newton; D monotone increasing in m.
        float Lb = c0 - MCL, Rb = c0 + MCL;
        m = c0;
        #pragma unroll
        for (int t = 0; t < NNEWT; ++t) {
            const float r0 = sig(a0, m), r1 = sig(a1, m);
            const float S = (v0 ? r0 : 0.0f) + (v1 ? r1 : 0.0f);
            const float T = (v0 ? r0 * (1.0f - r0) : 0.0f)
                          + (v1 ? r1 * (1.0f - r1) : 0.0f);
            const float Stot = wave_reduce_bcast(S) + below;
            const float Ttot = wave_reduce_bcast(T);
            const float D  = Stot * (1.0f / (float)S_DIM) - 0.5f;
            const float Dp = Ttot * (30.0f / (float)S_DIM);
            if (D > 0.0f) Rb = m; else Lb = m;
            float mn = m - D * __builtin_amdgcn_rcpf(Dp + 1e-20f);
            if (!(mn > Lb && mn < Rb)) mn = (Lb + Rb) * 0.5f;
            m = mn;
        }
    } else {
        // ---- Fallback (never taken for this input): ballot bisection +
        //      3 clamped full-width Newton, registers only. ----
        float lo = 0.0f, hi = 100.0f;
        #pragma unroll 1
        for (int t = 0; t < 16; ++t) {
            const float c = (lo + hi) * 0.5f;
            int cnt = 0;
            #pragma unroll
            for (int j = 0; j < EPL; ++j)
                cnt += __popcll(__ballot(xs[j] < c));
            if (cnt >= S_DIM / 2) hi = c; else lo = c;
        }
        m = (lo + hi) * 0.5f;
        #pragma unroll 1
        for (int t = 0; t < 3; ++t) {
            float S = 0.0f, T = 0.0f;
            #pragma unroll
            for (int j = 0; j < EPL; ++j) {
                const float r = sig(xs[j], m);
                S += r;
                T += r * (1.0f - r);
            }
            S = wave_reduce_bcast(S);
            T = wave_reduce_bcast(T);
            const float D  = S * (1.0f / (float)S_DIM) - 0.5f;
            const float Dp = T * (30.0f / (float)S_DIM);
            float step = D * __builtin_amdgcn_rcpf(Dp + 1e-12f);
            step = fminf(0.5f, fmaxf(-0.5f, step));
            m -= step;
        }
    }

    if (lane == 0) out[row] = m;
}

extern "C" void kernel_launch(void* const* d_in, const int* in_sizes, int n_in,
                              void* d_out, int out_size, void* d_ws, size_t ws_size,
                              hipStream_t stream) {
    const float* x = (const float*)d_in[0];
    float* out = (float*)d_out;
    const int bs = out_size;                   // 4096 rows, output [bs,1]
    const int blocks = (bs + WPB - 1) / WPB;   // 8 rows per 512-thread block
    dicho_kernel<<<blocks, 512, 0, stream>>>(x, out, bs);
}